// Round 7
// baseline (885.677 us; speedup 1.0000x reference)
//
#include <hip/hip_runtime.h>
#include <hip/hip_bf16.h>

// RNN: emb[x] -> xw GEMM -> 256 sequential tanh steps -> fused FC.
// All matmuls in f16 MFMA (16x16x32) with f32 accumulate.
// B=64, T=256, H=E=512, O=4.
//
// R7: k2 replaces the per-step __syncthreads with a split-phase barrier
// (LDS counter: release-arrive after epilogue, acquire-wait after the wave
// has consumed its OWN two kc groups). kc order is wave-relative
// (kc = (2w+j)&15, areg remapped so register indices stay compile-time):
// wave w produces rows 64w..64w+63 = kc 2w,2w+1, so it restarts on its own
// output with no wait. Waves desync by ~(epilogue+2kc) -> one wave's tanh
// VALU overlaps the sibling wave's MFMAs (was: lockstep, MfmaUtil+VALUBusy
// = 40%+41% non-overlapped).
// Safety: release fetch_add drains lgkmcnt (writes AND reads) before the
// count is visible; a wave passing "ctr >= 8t" therefore knows every wave
// finished step t-1 (all its reads of buf[(t+1)&1] included) before this
// wave's epilogue overwrites that buffer. Own-row reads (j=0,1) hit the
// wave's own prior writes (same-wave DS FIFO; compiler keeps order via
// may-alias). Riders: accB initialized from xw (saves 16 adds), t-loop
// unrolled x2 (loop-invariant buffer addresses).

typedef _Float16 f16;
typedef _Float16 f16x4 __attribute__((ext_vector_type(4)));
typedef _Float16 f16x8 __attribute__((ext_vector_type(8)));
typedef float    f32x4 __attribute__((ext_vector_type(4)));

// d_ws layout (bytes)
#define XWB_OFF   0u
#define XWB_BYTES (64u*256u*512u*2u)            // 16 MB: xw + biases, f16 [B*T][H]
#define AWHH_OFF  (XWB_OFF + XWB_BYTES)         // 512 KB: W_hh A-operand fragments
#define BWIH_OFF  (AWHH_OFF + 512u*1024u)       // 512 KB: W_ih B-operand fragments

#define HSTRIDE 528     // f16 col stride: 264 dwords = 8 mod 32 -> 2-way spread

// ---------------------------------------------------------------------------
// K0: pack W_hh (A-op layout) and W_ih (B-op layout) into fragment-linear
// f16: frag (kc, tile) at ((kc*32 + tile)*64 + lane)*8 f16.
// ---------------------------------------------------------------------------
__global__ __launch_bounds__(64) void k0_prep(const float* __restrict__ Whh,
                                              const float* __restrict__ Wih,
                                              f16* __restrict__ awhh,
                                              f16* __restrict__ bwih) {
    int id   = blockIdx.x;           // 0..1023
    int lane = threadIdx.x;          // 0..63
    bool is_ih = id >= 512;
    int lid = is_ih ? (id - 512) : id;       // = kc*32 + tile
    const float* src = is_ih ? Wih : Whh;
    f16* dst = is_ih ? bwih : awhh;
    int tile = lid & 31;
    int kc   = lid >> 5;
    int row  = tile * 16 + (lane & 15);
    int col0 = kc * 32 + (lane >> 4) * 8;
    const float* p = src + (size_t)row * 512 + col0;
    float4 v0 = *(const float4*)(p);
    float4 v1 = *(const float4*)(p + 4);
    f16x8 o;
    o[0] = (f16)v0.x; o[1] = (f16)v0.y; o[2] = (f16)v0.z; o[3] = (f16)v0.w;
    o[4] = (f16)v1.x; o[5] = (f16)v1.y; o[6] = (f16)v1.z; o[7] = (f16)v1.w;
    *(f16x8*)(dst + (size_t)lid * 512 + lane * 8) = o;
}

// ---------------------------------------------------------------------------
// K1: xwb[m][n] = sum_k emb[x[m]][k] * W_ih[n][k] + b_ih[n] + b_hh[n], f16.
// Double-buffered LDS staging; LDS-transpose epilogue for coalesced stores.
// ---------------------------------------------------------------------------
__global__ __launch_bounds__(256) void k1_xw(const int* __restrict__ x,
                                             const float* __restrict__ emb,
                                             const float* __restrict__ bih,
                                             const float* __restrict__ bhh,
                                             const f16* __restrict__ bwih,
                                             f16* __restrict__ xwb) {
    __shared__ f16 Bs[2][16384];     // 64 KB: double-buffered k-chunk of B frags
    int tid  = threadIdx.x;
    int wave = tid >> 6, lane = tid & 63;
    int quad = lane >> 4, l15 = lane & 15;
    int mrow0 = blockIdx.x * 64 + wave * 16;

    int arow_idx = x[mrow0 + l15];                  // gathered embedding row
    const float* arow = emb + (size_t)arow_idx * 512;

    f32x4 acc[32];
#pragma unroll
    for (int nt = 0; nt < 32; ++nt) acc[nt] = (f32x4){0.f, 0.f, 0.f, 0.f};

    float4 L[8];
    {
        const float4* s4 = (const float4*)bwih;
#pragma unroll
        for (int q = 0; q < 8; ++q) L[q] = s4[q * 256 + tid];
#pragma unroll
        for (int q = 0; q < 8; ++q) ((float4*)Bs[0])[q * 256 + tid] = L[q];
        const float4* s4b = (const float4*)(bwih + 16384);
#pragma unroll
        for (int q = 0; q < 8; ++q) L[q] = s4b[q * 256 + tid];
    }
    __syncthreads();

    for (int kc = 0; kc < 16; ++kc) {
        int cur = kc & 1;

        float4 a0 = *(const float4*)(arow + kc * 32 + quad * 8);
        float4 a1 = *(const float4*)(arow + kc * 32 + quad * 8 + 4);
        f16x8 af;
        af[0] = (f16)a0.x; af[1] = (f16)a0.y; af[2] = (f16)a0.z; af[3] = (f16)a0.w;
        af[4] = (f16)a1.x; af[5] = (f16)a1.y; af[6] = (f16)a1.z; af[7] = (f16)a1.w;

#pragma unroll
        for (int nt = 0; nt < 32; ++nt) {
            f16x8 bf = *(const f16x8*)(&Bs[cur][0] + nt * 512 + lane * 8);
            acc[nt] = __builtin_amdgcn_mfma_f32_16x16x32_f16(af, bf, acc[nt], 0, 0, 0);
        }

        if (kc < 15) {
#pragma unroll
            for (int q = 0; q < 8; ++q) ((float4*)Bs[cur ^ 1])[q * 256 + tid] = L[q];
        }
        __syncthreads();
        if (kc < 14) {
            const float4* s4 = (const float4*)(bwih + (size_t)(kc + 2) * 16384);
#pragma unroll
            for (int q = 0; q < 8; ++q) L[q] = s4[q * 256 + tid];
        }
    }
    __syncthreads();

    f16* trans = (f16*)Bs + (size_t)wave * 4224;
#pragma unroll
    for (int half = 0; half < 2; ++half) {
#pragma unroll
        for (int nt2 = 0; nt2 < 16; ++nt2) {
            int nt = half * 16 + nt2;
            int n = nt * 16 + l15;
            float bias = bih[n] + bhh[n];
#pragma unroll
            for (int r = 0; r < 4; ++r)
                trans[(quad * 4 + r) * 264 + nt2 * 16 + l15] =
                    (f16)(acc[nt][r] + bias);
        }
#pragma unroll
        for (int row = 0; row < 16; ++row) {
            f16x4 v = *(const f16x4*)(trans + row * 264 + lane * 4);
            *(f16x4*)(xwb + (size_t)(mrow0 + row) * 512 + half * 256 + lane * 4) = v;
        }
        __syncthreads();
    }
}

// ---------------------------------------------------------------------------
// K2 (ring): 16 WGs x 512 thr. WG owns batches wg*4..wg*4+3; h in 4 LDS cols
// (stride 528 f16, broadcast + 2-way spread = conflict-free). Wave w owns
// m-tiles 4w..4w+3 (rows 64w..64w+63). Wave-relative kc order; split-phase
// barrier via one LDS counter. areg[i] = kc (2w+i)&15 for i 0..11;
// fragS = i 12..15 (128 KB LDS).
// ---------------------------------------------------------------------------
__global__ __launch_bounds__(512, 2) void k2_ring(const f16* __restrict__ awhh,
                                                  const f16* __restrict__ xwb,
                                                  const float* __restrict__ Wfc,
                                                  const float* __restrict__ bfc,
                                                  float* __restrict__ out) {
    extern __shared__ char smem[];
    f16* fragS = (f16*)smem;                               // 131072 B
    f16* hbuf  = (f16*)(smem + 131072);                    // 8448 B
    unsigned* ctr = (unsigned*)(smem + 131072 + 8448);     // 4 B (+pad)

    int tid  = threadIdx.x;
    int wave = tid >> 6, lane = tid & 63;
    int quad = lane >> 4, n = lane & 15;
    int c    = n & 3;
    int mtb  = wave * 4;
    int w2   = wave << 1;

    // persistent A-frags, wave-relative: areg[p][i] holds kc=(2w+i)&15
    f16x8 areg[4][12];
#pragma unroll
    for (int p = 0; p < 4; ++p)
#pragma unroll
        for (int i = 0; i < 12; ++i) {
            int kc = (w2 + i) & 15;
            areg[p][i] = *(const f16x8*)(awhh +
                ((size_t)(kc * 32 + mtb + p) * 64 + lane) * 8);
        }

    // LDS frags: i = 12..15 (wave-private slots)
#pragma unroll
    for (int p = 0; p < 4; ++p)
#pragma unroll
        for (int j = 0; j < 4; ++j) {
            int kc = (w2 + 12 + j) & 15;
            f16x8 v = *(const f16x8*)(awhh +
                ((size_t)(kc * 32 + mtb + p) * 64 + lane) * 8);
            *(f16x8*)(fragS + (((mtb + p) * 4 + j) * 64 + lane) * 8) = v;
        }

    {
        unsigned int* hz = (unsigned int*)hbuf;
        for (int i = tid; i < 2 * 4 * HSTRIDE / 2; i += 512) hz[i] = 0u;
    }
    if (tid == 0) *ctr = 0u;
    __syncthreads();

    const f16* xptr = xwb + ((size_t)(blockIdx.x * 4 + c) * 256) * 512
                          + quad * 4;

    auto step = [&](int t, const f16* __restrict__ hc, f16* __restrict__ hn) {
        // xw prefetch (global; lands while own-kc MFMAs + spin run)
        f16x4 xw4[4];
#pragma unroll
        for (int p = 0; p < 4; ++p)
            xw4[p] = *(const f16x4*)(xptr + (mtb + p) * 16);
        xptr += 512;

        f32x4 accA[4];
#pragma unroll
        for (int p = 0; p < 4; ++p) accA[p] = (f32x4){0.f, 0.f, 0.f, 0.f};

        // j = 0,1: own rows (produced by this wave's previous epilogue)
#pragma unroll
        for (int j = 0; j < 2; ++j) {
            int kcj = (w2 + j) & 15;
            f16x8 bf = *(const f16x8*)(hc + c * HSTRIDE + kcj * 32 + quad * 8);
#pragma unroll
            for (int p = 0; p < 4; ++p)
                accA[p] = __builtin_amdgcn_mfma_f32_16x16x32_f16(
                    areg[p][j], bf, accA[p], 0, 0, 0);
        }

        // split-phase barrier WAIT: all waves must have finished step t-1
        unsigned lim = 8u * (unsigned)t;
        while (__hip_atomic_load(ctr, __ATOMIC_ACQUIRE,
                                 __HIP_MEMORY_SCOPE_WORKGROUP) < lim) { }

        // accB seeded from xw (folds the +xw add into the accumulator)
        f32x4 accB[4];
#pragma unroll
        for (int p = 0; p < 4; ++p)
#pragma unroll
            for (int r = 0; r < 4; ++r) accB[p][r] = (float)xw4[p][r];

        // j = 2..7 -> accA, register A
#pragma unroll
        for (int j = 2; j < 8; ++j) {
            int kcj = (w2 + j) & 15;
            f16x8 bf = *(const f16x8*)(hc + c * HSTRIDE + kcj * 32 + quad * 8);
#pragma unroll
            for (int p = 0; p < 4; ++p)
                accA[p] = __builtin_amdgcn_mfma_f32_16x16x32_f16(
                    areg[p][j], bf, accA[p], 0, 0, 0);
        }
        // j = 8..11 -> accB, register A
#pragma unroll
        for (int j = 8; j < 12; ++j) {
            int kcj = (w2 + j) & 15;
            f16x8 bf = *(const f16x8*)(hc + c * HSTRIDE + kcj * 32 + quad * 8);
#pragma unroll
            for (int p = 0; p < 4; ++p)
                accB[p] = __builtin_amdgcn_mfma_f32_16x16x32_f16(
                    areg[p][j], bf, accB[p], 0, 0, 0);
        }
        // j = 12..15 -> accB, LDS A
#pragma unroll
        for (int j = 0; j < 4; ++j) {
            int kcj = (w2 + 12 + j) & 15;
            f16x8 bf = *(const f16x8*)(hc + c * HSTRIDE + kcj * 32 + quad * 8);
#pragma unroll
            for (int p = 0; p < 4; ++p) {
                f16x8 af = *(const f16x8*)(fragS +
                    (((mtb + p) * 4 + j) * 64 + lane) * 8);
                accB[p] = __builtin_amdgcn_mfma_f32_16x16x32_f16(
                    af, bf, accB[p], 0, 0, 0);
            }
        }

        // epilogue: tanh, write own rows; then ARRIVE (release drains lgkm)
#pragma unroll
        for (int p = 0; p < 4; ++p) {
            int i0 = (mtb + p) * 16 + quad * 4;
            f16x4 hv;
#pragma unroll
            for (int r = 0; r < 4; ++r) {
                float z = accA[p][r] + accB[p][r];
                float e = __expf(2.f * z);       // bounded: |z| small
                hv[r] = (f16)((e - 1.f) * __builtin_amdgcn_rcpf(e + 1.f));
            }
            if (n < 4)
                *(f16x4*)(hn + c * HSTRIDE + i0) = hv;
        }
        if (lane == 0)
            (void)__hip_atomic_fetch_add(ctr, 1u, __ATOMIC_RELEASE,
                                         __HIP_MEMORY_SCOPE_WORKGROUP);
    };

    f16* bufA = hbuf;
    f16* bufB = hbuf + 4 * HSTRIDE;
    for (int th = 0; th < 128; ++th) {
        step(2 * th,     bufA, bufB);
        step(2 * th + 1, bufB, bufA);
    }
    __syncthreads();   // h(256) in bufA, all waves' writes visible

    // ---- fused FC
    float* red = (float*)smem;           // 512 floats (fragS dead)
    {
        int bb = tid >> 7;               // 0..3
        int oo = (tid >> 5) & 3;         // 0..3
        int sg = tid & 31;               // 0..31 -> 16 i each
        const f16* hrow = bufA + bb * HSTRIDE;
        const float* wrow = Wfc + (size_t)oo * 512;
        float s = 0.f;
#pragma unroll
        for (int ii = 0; ii < 16; ++ii) {
            int i = sg * 16 + ii;
            s += (float)hrow[i] * wrow[i];
        }
        __syncthreads();
        red[tid] = s;
    }
    __syncthreads();
    if (tid < 16) {
        int bb = tid >> 2, oo = tid & 3;
        float s = 0.f;
#pragma unroll
        for (int sg = 0; sg < 32; ++sg) s += red[(bb * 4 + oo) * 32 + sg];
        out[(blockIdx.x * 4 + bb) * 4 + oo] = s + bfc[oo];
    }
}

// ---------------------------------------------------------------------------
// K2 fallback (64-KB LDS, barrier version, R6 structure with LKC=1).
// ---------------------------------------------------------------------------
__global__ __launch_bounds__(512, 2) void k2_small(const f16* __restrict__ awhh,
                                                   const f16* __restrict__ xwb,
                                                   const float* __restrict__ Wfc,
                                                   const float* __restrict__ bfc,
                                                   float* __restrict__ out) {
    constexpr int LKC = 1, SKC = 3;
    extern __shared__ char smem[];
    f16* fragS = (f16*)smem;                               // 32768 B
    f16* hbuf  = (f16*)(smem + 32768);

    int tid  = threadIdx.x;
    int wave = tid >> 6, lane = tid & 63;
    int quad = lane >> 4, n = lane & 15;
    int c    = n & 3;
    int mtb  = wave * 4;

    f16x8 areg[4][12];
#pragma unroll
    for (int p = 0; p < 4; ++p)
#pragma unroll
        for (int kc = 0; kc < 12; ++kc)
            areg[p][kc] = *(const f16x8*)(awhh +
                ((size_t)(kc * 32 + mtb + p) * 64 + lane) * 8);
#pragma unroll
    for (int p = 0; p < 4; ++p)
        for (int j = 0; j < LKC; ++j) {
            f16x8 v = *(const f16x8*)(awhh +
                ((size_t)((12 + j) * 32 + mtb + p) * 64 + lane) * 8);
            *(f16x8*)(fragS + (((mtb + p) * LKC + j) * 64 + lane) * 8) = v;
        }
    {
        unsigned int* hz = (unsigned int*)hbuf;
        for (int i = tid; i < 2 * 4 * HSTRIDE / 2; i += 512) hz[i] = 0u;
    }
    __syncthreads();

    const f16* xptr = xwb + ((size_t)(blockIdx.x * 4 + c) * 256) * 512
                          + quad * 4;

    for (int t = 0; t < 256; ++t) {
        const f16* hc = hbuf + (size_t)(t & 1) * 4 * HSTRIDE;
        f16*       hn = hbuf + (size_t)((t + 1) & 1) * 4 * HSTRIDE;

        f16x4 xw4[4];
#pragma unroll
        for (int p = 0; p < 4; ++p)
            xw4[p] = *(const f16x4*)(xptr + (mtb + p) * 16);
        xptr += 512;

        f16x8 sst[SKC][4];
#pragma unroll
        for (int q = 0; q < SKC; ++q)
#pragma unroll
            for (int p = 0; p < 4; ++p)
                sst[q][p] = *(const f16x8*)(awhh +
                    ((size_t)((12 + LKC + q) * 32 + mtb + p) * 64 + lane) * 8);

        f32x4 accA[4], accB[4];
#pragma unroll
        for (int p = 0; p < 4; ++p) {
            accA[p] = (f32x4){0.f, 0.f, 0.f, 0.f};
#pragma unroll
            for (int r = 0; r < 4; ++r) accB[p][r] = (float)xw4[p][r];
        }

#pragma unroll
        for (int kc = 0; kc < 8; ++kc) {
            f16x8 bf = *(const f16x8*)(hc + c * HSTRIDE + kc * 32 + quad * 8);
#pragma unroll
            for (int p = 0; p < 4; ++p)
                accA[p] = __builtin_amdgcn_mfma_f32_16x16x32_f16(
                    areg[p][kc], bf, accA[p], 0, 0, 0);
        }
#pragma unroll
        for (int kc = 8; kc < 12; ++kc) {
            f16x8 bf = *(const f16x8*)(hc + c * HSTRIDE + kc * 32 + quad * 8);
#pragma unroll
            for (int p = 0; p < 4; ++p)
                accB[p] = __builtin_amdgcn_mfma_f32_16x16x32_f16(
                    areg[p][kc], bf, accB[p], 0, 0, 0);
        }
#pragma unroll
        for (int j = 0; j < LKC; ++j) {
            int kc = 12 + j;
            f16x8 bf = *(const f16x8*)(hc + c * HSTRIDE + kc * 32 + quad * 8);
#pragma unroll
            for (int p = 0; p < 4; ++p) {
                f16x8 af = *(const f16x8*)(fragS +
                    (((mtb + p) * LKC + j) * 64 + lane) * 8);
                accB[p] = __builtin_amdgcn_mfma_f32_16x16x32_f16(
                    af, bf, accB[p], 0, 0, 0);
            }
        }
#pragma unroll
        for (int q = 0; q < SKC; ++q) {
            int kc = 12 + LKC + q;
            f16x8 bf = *(const f16x8*)(hc + c * HSTRIDE + kc * 32 + quad * 8);
#pragma unroll
            for (int p = 0; p < 4; ++p)
                accB[p] = __builtin_amdgcn_mfma_f32_16x16x32_f16(
                    sst[q][p], bf, accB[p], 0, 0, 0);
        }

#pragma unroll
        for (int p = 0; p < 4; ++p) {
            int i0 = (mtb + p) * 16 + quad * 4;
            f16x4 hv;
#pragma unroll
            for (int r = 0; r < 4; ++r) {
                float z = accA[p][r] + accB[p][r];
                float e = __expf(2.f * z);
                hv[r] = (f16)((e - 1.f) * __builtin_amdgcn_rcpf(e + 1.f));
            }
            if (n < 4)
                *(f16x4*)(hn + c * HSTRIDE + i0) = hv;
        }
        __syncthreads();
    }

    float* red = (float*)smem;
    {
        int bb = tid >> 7, oo = (tid >> 5) & 3, sg = tid & 31;
        const f16* hrow = hbuf + bb * HSTRIDE;
        const float* wrow = Wfc + (size_t)oo * 512;
        float s = 0.f;
#pragma unroll
        for (int ii = 0; ii < 16; ++ii) s += (float)hrow[sg * 16 + ii] * wrow[sg * 16 + ii];
        __syncthreads();
        red[tid] = s;
    }
    __syncthreads();
    if (tid < 16) {
        int bb = tid >> 2, oo = tid & 3;
        float s = 0.f;
#pragma unroll
        for (int sg = 0; sg < 32; ++sg) s += red[(bb * 4 + oo) * 32 + sg];
        out[(blockIdx.x * 4 + bb) * 4 + oo] = s + bfc[oo];
    }
}

extern "C" void kernel_launch(void* const* d_in, const int* in_sizes, int n_in,
                              void* d_out, int out_size, void* d_ws, size_t ws_size,
                              hipStream_t stream) {
    const int*   x   = (const int*)d_in[0];
    const float* emb = (const float*)d_in[1];
    const float* Wih = (const float*)d_in[2];
    const float* Whh = (const float*)d_in[3];
    const float* bih = (const float*)d_in[4];
    const float* bhh = (const float*)d_in[5];
    const float* Wfc = (const float*)d_in[6];
    const float* bfc = (const float*)d_in[7];
    float* out = (float*)d_out;

    char* ws = (char*)d_ws;
    f16* xwb  = (f16*)(ws + XWB_OFF);
    f16* awhh = (f16*)(ws + AWHH_OFF);
    f16* bwih = (f16*)(ws + BWIH_OFF);

    hipLaunchKernelGGL(k0_prep, dim3(1024), dim3(64),  0, stream, Whh, Wih, awhh, bwih);
    hipLaunchKernelGGL(k1_xw,   dim3(256),  dim3(256), 0, stream, x, emb, bih, bhh, bwih, xwb);

    const int HB = 2 * 4 * HSTRIDE * 2;                 // 8448 B
    const int LDS_BIG   = 131072 + HB + 16;             // 139536
    const int LDS_SMALL = 32768 + HB;                   // 41216
    int dev = 0;
    (void)hipGetDevice(&dev);
    int maxlds = 0;
    (void)hipDeviceGetAttribute(&maxlds, hipDeviceAttributeMaxSharedMemoryPerBlock, dev);
    bool big = maxlds >= LDS_BIG;
    if (big)
        big = (hipFuncSetAttribute((const void*)&k2_ring,
                                   hipFuncAttributeMaxDynamicSharedMemorySize,
                                   LDS_BIG) == hipSuccess);
    if (big) {
        hipLaunchKernelGGL(k2_ring, dim3(16), dim3(512), LDS_BIG, stream,
                           awhh, xwb, Wfc, bfc, out);
    } else {
        (void)hipFuncSetAttribute((const void*)&k2_small,
                                  hipFuncAttributeMaxDynamicSharedMemorySize,
                                  LDS_SMALL);
        hipLaunchKernelGGL(k2_small, dim3(16), dim3(512), LDS_SMALL, stream,
                          awhh, xwb, Wfc, bfc, out);
    }
}